// Round 4
// baseline (81.561 us; speedup 1.0000x reference)
//
#include <hip/hip_runtime.h>
#include <math.h>

#define DDIM 512
#define THREADS 256
#define BT 128          // block tile (M and N)
#define NT 32           // N / BT tile grid dimension
#define NCH 64          // 64-wide column chunks for partials

typedef __attribute__((ext_vector_type(8))) __bf16 bf16x8;
typedef __attribute__((ext_vector_type(4))) float f32x4;
typedef __attribute__((ext_vector_type(8))) unsigned short ushort8;

__device__ __forceinline__ float bf2f(unsigned short u) {
  union { unsigned int i; float f; } v; v.i = ((unsigned int)u) << 16; return v.f;
}
__device__ __forceinline__ unsigned short f2bf(float f) {
  unsigned int u = __builtin_bit_cast(unsigned int, f);
  return (unsigned short)((u + 0x7fffu + ((u >> 16) & 1u)) >> 16);
}

// ---- kernel 1: normalize rows w and w+B to bf16, compute pos[w]=dot/temp ----
__global__ void k_prep(const float* __restrict__ zi, const float* __restrict__ zj,
                       const float* __restrict__ tempp,
                       unsigned short* __restrict__ znb, float* __restrict__ pos,
                       int B) {
  int wv = (blockIdx.x * blockDim.x + threadIdx.x) >> 6;
  int lane = threadIdx.x & 63;
  if (wv >= B) return;
  const float* a = zi + (size_t)wv * DDIM;
  const float* b = zj + (size_t)wv * DDIM;
  float4 a0 = *(const float4*)(a + lane * 8);
  float4 a1 = *(const float4*)(a + lane * 8 + 4);
  float4 b0 = *(const float4*)(b + lane * 8);
  float4 b1 = *(const float4*)(b + lane * 8 + 4);
  float av[8] = {a0.x, a0.y, a0.z, a0.w, a1.x, a1.y, a1.z, a1.w};
  float bv[8] = {b0.x, b0.y, b0.z, b0.w, b1.x, b1.y, b1.z, b1.w};
  float sa = 0.f, sb = 0.f;
#pragma unroll
  for (int i = 0; i < 8; ++i) { sa = fmaf(av[i], av[i], sa); sb = fmaf(bv[i], bv[i], sb); }
#pragma unroll
  for (int off = 32; off; off >>= 1) { sa += __shfl_xor(sa, off, 64); sb += __shfl_xor(sb, off, 64); }
  float ia = 1.f / fmaxf(sqrtf(sa), 1e-8f);
  float ib = 1.f / fmaxf(sqrtf(sb), 1e-8f);
  ushort8 ua, ub;
  float fa[8], fb[8];
#pragma unroll
  for (int i = 0; i < 8; ++i) {
    unsigned short x = f2bf(av[i] * ia); ua[i] = x; fa[i] = bf2f(x);
    unsigned short y = f2bf(bv[i] * ib); ub[i] = y; fb[i] = bf2f(y);
  }
  *(ushort8*)(znb + (size_t)wv * DDIM + lane * 8) = ua;
  *(ushort8*)(znb + (size_t)(wv + B) * DDIM + lane * 8) = ub;
  float pd = 0.f;
#pragma unroll
  for (int i = 0; i < 8; ++i) pd = fmaf(fa[i], fb[i], pd);
#pragma unroll
  for (int off = 32; off; off >>= 1) pd += __shfl_xor(pd, off, 64);
  if (lane == 0) {
    float p = pd / tempp[0];
    pos[wv] = p; pos[wv + B] = p;
  }
}

// ---- kernel 2: LDS-free MFMA Gram tiles (fragments direct from L2) ----------
__global__ __launch_bounds__(THREADS) void k_main(
    const unsigned short* __restrict__ znb, const float* __restrict__ pos,
    const float* __restrict__ tempp, float* __restrict__ partS,
    float* __restrict__ partC, int B) {
  // decode upper-triangular tile (bi <= bj)
  int l = blockIdx.x;
  int bi = 0;
  while (l >= NT - bi) { l -= NT - bi; ++bi; }
  const int bj = bi + l;
  const int r0 = bi * BT, c0 = bj * BT;
  const bool diag = (bi == bj);
  const float invt = 1.0f / tempp[0];

  const int t = threadIdx.x;
  const int lane = t & 63;
  const int wave = t >> 6;
  const int wr = wave >> 1, wc = wave & 1;   // 2x2 wave grid, each 64x64
  const int cl = lane & 15, g = lane >> 4;

  f32x4 acc[4][4];
#pragma unroll
  for (int m = 0; m < 4; ++m)
#pragma unroll
    for (int n = 0; n < 4; ++n) acc[m][n] = (f32x4){0.f, 0.f, 0.f, 0.f};

  // Per-lane base pointers: A rows r0+wr*64+m*16+cl, B rows c0+wc*64+n*16+cl,
  // k-offset g*8. Each 16B load covers k..k+7; lanes g=0..3 of a row form 64B.
  const unsigned short* baseA = znb + (size_t)(r0 + wr * 64 + cl) * DDIM + g * 8;
  const unsigned short* baseB = znb + (size_t)(c0 + wc * 64 + cl) * DDIM + g * 8;

#pragma unroll 2
  for (int kt = 0; kt < DDIM / 32; ++kt) {   // 16 K-steps of 32
    const int kk = kt * 32;
    bf16x8 aF[4], bF[4];
#pragma unroll
    for (int m = 0; m < 4; ++m)
      aF[m] = *(const bf16x8*)(baseA + (size_t)(m * 16) * DDIM + kk);
#pragma unroll
    for (int n = 0; n < 4; ++n)
      bF[n] = *(const bf16x8*)(baseB + (size_t)(n * 16) * DDIM + kk);
#pragma unroll
    for (int m = 0; m < 4; ++m)
#pragma unroll
      for (int n = 0; n < 4; ++n)
        acc[m][n] = __builtin_amdgcn_mfma_f32_16x16x32_bf16(aF[m], bF[n], acc[m][n], 0, 0, 0);
  }

  // ---- epilogue: row partials (always) + col partials (off-diag tiles) ----
  int growv[16], gpartr[16];
  float pvr[16];
#pragma unroll
  for (int m = 0; m < 4; ++m)
#pragma unroll
    for (int reg = 0; reg < 4; ++reg) {
      int idx = m * 4 + reg;
      int grow = r0 + wr * 64 + m * 16 + g * 4 + reg;
      growv[idx] = grow;
      gpartr[idx] = (grow < B) ? grow + B : grow - B;
      pvr[idx] = pos[grow];
    }
  int gcolv[4], gpartc[4];
  float pvc[4];
#pragma unroll
  for (int n = 0; n < 4; ++n) {
    int gcol = c0 + wc * 64 + n * 16 + cl;
    gcolv[n] = gcol;
    gpartc[n] = (gcol < B) ? gcol + B : gcol - B;
    pvc[n] = pos[gcol];
  }

  float ssr[16], ccr[16], ssc[4], ccc[4];
#pragma unroll
  for (int i = 0; i < 16; ++i) { ssr[i] = 0.f; ccr[i] = 0.f; }
#pragma unroll
  for (int n = 0; n < 4; ++n) { ssc[n] = 0.f; ccc[n] = 0.f; }

#pragma unroll
  for (int m = 0; m < 4; ++m)
#pragma unroll
    for (int n = 0; n < 4; ++n)
#pragma unroll
      for (int reg = 0; reg < 4; ++reg) {
        const int idx = m * 4 + reg;
        float val = acc[m][n][reg] * invt;
        float e = __expf(val);
        bool isd = diag && (gcolv[n] == growv[idx]);
        if (!isd) {
          ssr[idx] += e;
          ccr[idx] += (gcolv[n] != gpartr[idx] && val > pvr[idx]) ? 1.f : 0.f;
        }
        if (!diag) {
          ssc[n] += e;
          ccc[n] += (growv[idx] != gpartc[n] && val > pvc[n]) ? 1.f : 0.f;
        }
      }

  // row partials: reduce over cl (16 lanes), write chunk 2*bj + wc
  const int chR = bj * 2 + wc;
#pragma unroll
  for (int idx = 0; idx < 16; ++idx) {
    float s = ssr[idx], c = ccr[idx];
#pragma unroll
    for (int off = 1; off < 16; off <<= 1) {
      s += __shfl_xor(s, off, 64);
      c += __shfl_xor(c, off, 64);
    }
    if (cl == 0) {
      partS[(size_t)growv[idx] * NCH + chR] = s;
      partC[(size_t)growv[idx] * NCH + chR] = c;
    }
  }
  // col partials: reduce over g (xor 16,32), write chunk 2*bi + wr
  if (!diag) {
    const int chC = bi * 2 + wr;
#pragma unroll
    for (int n = 0; n < 4; ++n) {
      float s = ssc[n], c = ccc[n];
      s += __shfl_xor(s, 16, 64); c += __shfl_xor(c, 16, 64);
      s += __shfl_xor(s, 32, 64); c += __shfl_xor(c, 32, 64);
      if (g == 0) {
        partS[(size_t)gcolv[n] * NCH + chC] = s;
        partC[(size_t)gcolv[n] * NCH + chC] = c;
      }
    }
  }
}

// ---- kernel 3: per-row combine of 64 chunks -> rowLoss, rowCnt ----
__global__ void k_rowfin(const float* __restrict__ partS, const float* __restrict__ partC,
                         const float* __restrict__ pos, float* __restrict__ rowL,
                         float* __restrict__ rowC, int N) {
  int r = (blockIdx.x * blockDim.x + threadIdx.x) >> 6;
  int lane = threadIdx.x & 63;
  if (r >= N) return;
  float s = partS[(size_t)r * NCH + lane];
  float c = partC[(size_t)r * NCH + lane];
#pragma unroll
  for (int off = 32; off; off >>= 1) { s += __shfl_xor(s, off, 64); c += __shfl_xor(c, off, 64); }
  if (lane == 0) {
    rowL[r] = logf(s) - pos[r];
    rowC[r] = c;
  }
}

// ---- kernel 4: final reduction to (loss, avg_rank) ----
__global__ void k_final(const float* __restrict__ rowL, const float* __restrict__ rowC,
                        float* __restrict__ out, int N) {
  float ls = 0.f, cs = 0.f;
  for (int r = threadIdx.x; r < N; r += THREADS) { ls += rowL[r]; cs += rowC[r]; }
  __shared__ float l[THREADS], c[THREADS];
  l[threadIdx.x] = ls; c[threadIdx.x] = cs;
  __syncthreads();
  for (int off = THREADS / 2; off; off >>= 1) {
    if (threadIdx.x < off) { l[threadIdx.x] += l[threadIdx.x + off]; c[threadIdx.x] += c[threadIdx.x + off]; }
    __syncthreads();
  }
  if (threadIdx.x == 0) { out[0] = l[0] / (float)N; out[1] = c[0] / (float)N; }
}

extern "C" void kernel_launch(void* const* d_in, const int* in_sizes, int n_in,
                              void* d_out, int out_size, void* d_ws, size_t ws_size,
                              hipStream_t stream) {
  const float* zi = (const float*)d_in[0];
  const float* zj = (const float*)d_in[1];
  const float* temp = (const float*)d_in[2];
  float* out = (float*)d_out;

  const int B = in_sizes[0] / DDIM;   // 2048
  const int N = 2 * B;                // 4096

  unsigned short* znb = (unsigned short*)d_ws;          // N*DDIM bf16 = 4 MB
  float* fws = (float*)(znb + (size_t)N * DDIM);
  float* pos   = fws;                                    // N
  float* partS = pos + N;                                // N*NCH = 1 MB
  float* partC = partS + (size_t)N * NCH;                // N*NCH = 1 MB
  float* rowL  = partC + (size_t)N * NCH;                // N
  float* rowC  = rowL + N;                               // N

  k_prep<<<(B * 64) / THREADS, THREADS, 0, stream>>>(zi, zj, temp, znb, pos, B);
  const int ntiles = NT * (NT + 1) / 2;                  // 528 triangular tiles
  k_main<<<ntiles, THREADS, 0, stream>>>(znb, pos, temp, partS, partC, B);
  k_rowfin<<<(N * 64) / THREADS, THREADS, 0, stream>>>(partS, partC, pos, rowL, rowC, N);
  k_final<<<1, THREADS, 0, stream>>>(rowL, rowC, out, N);
}

// Round 5
// 49.744 us; speedup vs baseline: 1.6396x; 1.6396x over previous
//
#include <hip/hip_runtime.h>
#include <math.h>

#define DDIM 512
#define THREADS 256
#define BT 128          // block tile (M and N)
#define BK 64           // K-step (one staged LDS tile)
#define NT 32           // N / BT tile grid dimension
#define NCH 64          // 64-wide column chunks for partials

typedef __attribute__((ext_vector_type(8))) __bf16 bf16x8;
typedef __attribute__((ext_vector_type(4))) float f32x4;
typedef __attribute__((ext_vector_type(8))) unsigned short ushort8;

__device__ __forceinline__ float bf2f(unsigned short u) {
  union { unsigned int i; float f; } v; v.i = ((unsigned int)u) << 16; return v.f;
}
__device__ __forceinline__ unsigned short f2bf(float f) {
  unsigned int u = __builtin_bit_cast(unsigned int, f);
  return (unsigned short)((u + 0x7fffu + ((u >> 16) & 1u)) >> 16);
}

#define GLOAD_LDS16(gp, lp)                                                   \
  __builtin_amdgcn_global_load_lds(                                           \
      (const __attribute__((address_space(1))) unsigned int*)(gp),            \
      (__attribute__((address_space(3))) unsigned int*)(lp), 16, 0, 0)

// ---- kernel 1: normalize rows w and w+B to bf16, compute pos[w]=dot/temp ----
__global__ void k_prep(const float* __restrict__ zi, const float* __restrict__ zj,
                       const float* __restrict__ tempp,
                       unsigned short* __restrict__ znb, float* __restrict__ pos,
                       int B) {
  int wv = (blockIdx.x * blockDim.x + threadIdx.x) >> 6;
  int lane = threadIdx.x & 63;
  if (wv >= B) return;
  const float* a = zi + (size_t)wv * DDIM;
  const float* b = zj + (size_t)wv * DDIM;
  float4 a0 = *(const float4*)(a + lane * 8);
  float4 a1 = *(const float4*)(a + lane * 8 + 4);
  float4 b0 = *(const float4*)(b + lane * 8);
  float4 b1 = *(const float4*)(b + lane * 8 + 4);
  float av[8] = {a0.x, a0.y, a0.z, a0.w, a1.x, a1.y, a1.z, a1.w};
  float bv[8] = {b0.x, b0.y, b0.z, b0.w, b1.x, b1.y, b1.z, b1.w};
  float sa = 0.f, sb = 0.f;
#pragma unroll
  for (int i = 0; i < 8; ++i) { sa = fmaf(av[i], av[i], sa); sb = fmaf(bv[i], bv[i], sb); }
#pragma unroll
  for (int off = 32; off; off >>= 1) { sa += __shfl_xor(sa, off, 64); sb += __shfl_xor(sb, off, 64); }
  float ia = 1.f / fmaxf(sqrtf(sa), 1e-8f);
  float ib = 1.f / fmaxf(sqrtf(sb), 1e-8f);
  ushort8 ua, ub;
  float fa[8], fb[8];
#pragma unroll
  for (int i = 0; i < 8; ++i) {
    unsigned short x = f2bf(av[i] * ia); ua[i] = x; fa[i] = bf2f(x);
    unsigned short y = f2bf(bv[i] * ib); ub[i] = y; fb[i] = bf2f(y);
  }
  *(ushort8*)(znb + (size_t)wv * DDIM + lane * 8) = ua;
  *(ushort8*)(znb + (size_t)(wv + B) * DDIM + lane * 8) = ub;
  float pd = 0.f;
#pragma unroll
  for (int i = 0; i < 8; ++i) pd = fmaf(fa[i], fb[i], pd);
#pragma unroll
  for (int off = 32; off; off >>= 1) pd += __shfl_xor(pd, off, 64);
  if (lane == 0) {
    float p = pd / tempp[0];
    pos[wv] = p; pos[wv + B] = p;
  }
}

// stage one 128x64 bf16 panel into LDS (linear dest, swizzled global source)
__device__ __forceinline__ void stage_tile(const unsigned short* __restrict__ znb,
                                           int panel0, int k0, unsigned char* dst,
                                           int wave, int lane) {
  const int srow_in = lane >> 3;                  // 0..7 within 8-row region
  const int slog = (lane & 7) ^ srow_in;          // logical 16B k-slot (involution)
#pragma unroll
  for (int j = 0; j < 4; ++j) {
    const int ww = wave * 4 + j;                  // region 0..15
    const int row = 8 * ww + srow_in;
    GLOAD_LDS16(znb + (size_t)(panel0 + row) * DDIM + k0 + slog * 8, dst + ww * 1024);
  }
}

// ---- kernel 2: symmetric MFMA Gram tiles, counted-vmcnt double-buffer ------
__global__ __launch_bounds__(THREADS, 2) void k_main(
    const unsigned short* __restrict__ znb, const float* __restrict__ pos,
    const float* __restrict__ tempp, float* __restrict__ partS,
    float* __restrict__ partC, int B) {
  // decode upper-triangular tile (bi <= bj)
  int l = blockIdx.x;
  int bi = 0;
  while (l >= NT - bi) { l -= NT - bi; ++bi; }
  const int bj = bi + l;
  const int r0 = bi * BT, c0 = bj * BT;
  const bool diag = (bi == bj);
  const float invt = 1.0f / tempp[0];

  __shared__ __align__(16) unsigned char sA[2][BT * BK * 2];  // 2 x 16 KB
  __shared__ __align__(16) unsigned char sB[2][BT * BK * 2];  // 2 x 16 KB

  const int t = threadIdx.x;
  const int lane = t & 63;
  const int wave = t >> 6;
  const int wr = wave >> 1, wc = wave & 1;   // 2x2 wave grid, each 64x64
  const int cl = lane & 15, g = lane >> 4;

  f32x4 acc[4][4];
#pragma unroll
  for (int m = 0; m < 4; ++m)
#pragma unroll
    for (int n = 0; n < 4; ++n) acc[m][n] = (f32x4){0.f, 0.f, 0.f, 0.f};

  // prologue: stage K-tile 0 (always stage both panels; diag stages a copy)
  stage_tile(znb, r0, 0, sA[0], wave, lane);
  stage_tile(znb, c0, 0, sB[0], wave, lane);

#pragma unroll
  for (int kt = 0; kt < DDIM / BK; ++kt) {   // 8 K-tiles
    const int cur = kt & 1;
    if (kt < DDIM / BK - 1) {
      // issue next tile's loads into the other buffer (8 per wave)
      stage_tile(znb, r0, (kt + 1) * BK, sA[cur ^ 1], wave, lane);
      stage_tile(znb, c0, (kt + 1) * BK, sB[cur ^ 1], wave, lane);
      // wait only for the PREVIOUS tile's 8 loads; prefetch stays in flight
      asm volatile("s_waitcnt vmcnt(8)" ::: "memory");
    } else {
      asm volatile("s_waitcnt vmcnt(0)" ::: "memory");
    }
    __builtin_amdgcn_sched_barrier(0);
    __builtin_amdgcn_s_barrier();            // buffer `cur` ready for all waves

    const unsigned char* pA = sA[cur];
    const unsigned char* pB = sB[cur];
#pragma unroll
    for (int ks = 0; ks < 2; ++ks) {
      const int phys = (g + ks * 4) ^ (cl & 7);
      bf16x8 aF[4], bF[4];
#pragma unroll
      for (int m = 0; m < 4; ++m)
        aF[m] = *(const bf16x8*)(pA + (wr * 64 + m * 16 + cl) * 128 + phys * 16);
#pragma unroll
      for (int n = 0; n < 4; ++n)
        bF[n] = *(const bf16x8*)(pB + (wc * 64 + n * 16 + cl) * 128 + phys * 16);
#pragma unroll
      for (int m = 0; m < 4; ++m)
#pragma unroll
        for (int n = 0; n < 4; ++n)
          acc[m][n] = __builtin_amdgcn_mfma_f32_16x16x32_bf16(aF[m], bF[n], acc[m][n], 0, 0, 0);
    }
    if (kt < DDIM / BK - 1)
      __builtin_amdgcn_s_barrier();          // all waves done reading `cur`
  }

  // ---- epilogue: row partials (always) + col partials (off-diag tiles) ----
  int growv[16], gpartr[16];
  float pvr[16];
#pragma unroll
  for (int m = 0; m < 4; ++m)
#pragma unroll
    for (int reg = 0; reg < 4; ++reg) {
      int idx = m * 4 + reg;
      int grow = r0 + wr * 64 + m * 16 + g * 4 + reg;
      growv[idx] = grow;
      gpartr[idx] = (grow < B) ? grow + B : grow - B;
      pvr[idx] = pos[grow];
    }
  int gcolv[4], gpartc[4];
  float pvc[4];
#pragma unroll
  for (int n = 0; n < 4; ++n) {
    int gcol = c0 + wc * 64 + n * 16 + cl;
    gcolv[n] = gcol;
    gpartc[n] = (gcol < B) ? gcol + B : gcol - B;
    pvc[n] = pos[gcol];
  }

  float ssr[16], ccr[16], ssc[4], ccc[4];
#pragma unroll
  for (int i = 0; i < 16; ++i) { ssr[i] = 0.f; ccr[i] = 0.f; }
#pragma unroll
  for (int n = 0; n < 4; ++n) { ssc[n] = 0.f; ccc[n] = 0.f; }

#pragma unroll
  for (int m = 0; m < 4; ++m)
#pragma unroll
    for (int n = 0; n < 4; ++n)
#pragma unroll
      for (int reg = 0; reg < 4; ++reg) {
        const int idx = m * 4 + reg;
        float val = acc[m][n][reg] * invt;
        float e = __expf(val);
        bool isd = diag && (gcolv[n] == growv[idx]);
        if (!isd) {
          ssr[idx] += e;
          ccr[idx] += (gcolv[n] != gpartr[idx] && val > pvr[idx]) ? 1.f : 0.f;
        }
        if (!diag) {
          ssc[n] += e;
          ccc[n] += (growv[idx] != gpartc[n] && val > pvc[n]) ? 1.f : 0.f;
        }
      }

  // row partials: reduce over cl (16 lanes), write chunk 2*bj + wc
  const int chR = bj * 2 + wc;
#pragma unroll
  for (int idx = 0; idx < 16; ++idx) {
    float s = ssr[idx], c = ccr[idx];
#pragma unroll
    for (int off = 1; off < 16; off <<= 1) {
      s += __shfl_xor(s, off, 64);
      c += __shfl_xor(c, off, 64);
    }
    if (cl == 0) {
      partS[(size_t)growv[idx] * NCH + chR] = s;
      partC[(size_t)growv[idx] * NCH + chR] = c;
    }
  }
  // col partials: reduce over g (xor 16,32), write chunk 2*bi + wr
  if (!diag) {
    const int chC = bi * 2 + wr;
#pragma unroll
    for (int n = 0; n < 4; ++n) {
      float s = ssc[n], c = ccc[n];
      s += __shfl_xor(s, 16, 64); c += __shfl_xor(c, 16, 64);
      s += __shfl_xor(s, 32, 64); c += __shfl_xor(c, 32, 64);
      if (g == 0) {
        partS[(size_t)gcolv[n] * NCH + chC] = s;
        partC[(size_t)gcolv[n] * NCH + chC] = c;
      }
    }
  }
}

// ---- kernel 3: per-row combine of 64 chunks -> rowLoss, rowCnt ----
__global__ void k_rowfin(const float* __restrict__ partS, const float* __restrict__ partC,
                         const float* __restrict__ pos, float* __restrict__ rowL,
                         float* __restrict__ rowC, int N) {
  int r = (blockIdx.x * blockDim.x + threadIdx.x) >> 6;
  int lane = threadIdx.x & 63;
  if (r >= N) return;
  float s = partS[(size_t)r * NCH + lane];
  float c = partC[(size_t)r * NCH + lane];
#pragma unroll
  for (int off = 32; off; off >>= 1) { s += __shfl_xor(s, off, 64); c += __shfl_xor(c, off, 64); }
  if (lane == 0) {
    rowL[r] = logf(s) - pos[r];
    rowC[r] = c;
  }
}

// ---- kernel 4: final reduction to (loss, avg_rank) ----
__global__ void k_final(const float* __restrict__ rowL, const float* __restrict__ rowC,
                        float* __restrict__ out, int N) {
  float ls = 0.f, cs = 0.f;
  for (int r = threadIdx.x; r < N; r += THREADS) { ls += rowL[r]; cs += rowC[r]; }
  __shared__ float l[THREADS], c[THREADS];
  l[threadIdx.x] = ls; c[threadIdx.x] = cs;
  __syncthreads();
  for (int off = THREADS / 2; off; off >>= 1) {
    if (threadIdx.x < off) { l[threadIdx.x] += l[threadIdx.x + off]; c[threadIdx.x] += c[threadIdx.x + off]; }
    __syncthreads();
  }
  if (threadIdx.x == 0) { out[0] = l[0] / (float)N; out[1] = c[0] / (float)N; }
}

extern "C" void kernel_launch(void* const* d_in, const int* in_sizes, int n_in,
                              void* d_out, int out_size, void* d_ws, size_t ws_size,
                              hipStream_t stream) {
  const float* zi = (const float*)d_in[0];
  const float* zj = (const float*)d_in[1];
  const float* temp = (const float*)d_in[2];
  float* out = (float*)d_out;

  const int B = in_sizes[0] / DDIM;   // 2048
  const int N = 2 * B;                // 4096

  unsigned short* znb = (unsigned short*)d_ws;          // N*DDIM bf16 = 4 MB
  float* fws = (float*)(znb + (size_t)N * DDIM);
  float* pos   = fws;                                    // N
  float* partS = pos + N;                                // N*NCH = 1 MB
  float* partC = partS + (size_t)N * NCH;                // N*NCH = 1 MB
  float* rowL  = partC + (size_t)N * NCH;                // N
  float* rowC  = rowL + N;                               // N

  k_prep<<<(B * 64) / THREADS, THREADS, 0, stream>>>(zi, zj, temp, znb, pos, B);
  const int ntiles = NT * (NT + 1) / 2;                  // 528 triangular tiles
  k_main<<<ntiles, THREADS, 0, stream>>>(znb, pos, temp, partS, partC, B);
  k_rowfin<<<(N * 64) / THREADS, THREADS, 0, stream>>>(partS, partC, pos, rowL, rowC, N);
  k_final<<<1, THREADS, 0, stream>>>(rowL, rowC, out, N);
}